// Round 5
// baseline (3088.332 us; speedup 1.0000x reference)
//
#include <hip/hip_runtime.h>
#include <cstddef>
#include <cstdint>

// Problem dims: B=16, L=256, V=32000, E=256, H=256
// ws layout (bytes):
//   [0, 65536)     h exchange: [2 dir][2 parity][16 b][256 j] u32 = (tag<<16)|bf16(h)
//   [65536, +2MB)  Xb bf16 [4096 m][256 e], m = t*16 + b
//   [+2MB, +3MB)   Wcat bf16 [2048 n][256 k] (rows 0..1023 = W_ih_f, 1024.. = W_ih_b)
//   [+3MB, +36.5MB) Gm f32 [4096 m][2048 n], n = dir*1024 + gate*256 + j
#define HX_OFF   0
#define MS_BYTES 65536
#define X_OFF    65536
#define W_OFF    (X_OFF + 4096 * 256 * 2)
#define G_OFF    (W_OFF + 2048 * 256 * 2)

typedef __attribute__((ext_vector_type(8))) short short8;
typedef __attribute__((ext_vector_type(4))) float f32x4;
typedef __attribute__((ext_vector_type(4))) unsigned uint4v;

__device__ __forceinline__ unsigned short f2bf(float f) {
  unsigned u = __builtin_bit_cast(unsigned, f);
  u = (u + 0x7fffu + ((u >> 16) & 1u)) >> 16;   // round-to-nearest-even
  return (unsigned short)u;
}
__device__ __forceinline__ float sigm_f(float x) {
  return __builtin_amdgcn_rcpf(1.f + __expf(-x));
}
__device__ __forceinline__ float tanh_f(float x) {
  return 1.f - 2.f * __builtin_amdgcn_rcpf(1.f + __expf(2.f * x));
}
// low16 of both u32 halves of q, packed into one u32 (2 bf16)
__device__ __forceinline__ unsigned pack_lo16(unsigned long long q) {
  return ((unsigned)q & 0xFFFFu) | ((unsigned)(q >> 32) << 16);
}

// ---------------- Phase 1: one-hot scan + embedding gather (bf16 out) -------
__global__ __launch_bounds__(256) void k_embed(const float* __restrict__ seq,
                                               const float* __restrict__ emb,
                                               unsigned short* __restrict__ xb) {
  const int m = blockIdx.x;          // m = t*16 + b
  const int t = m >> 4, b = m & 15;
  const float* row = seq + (size_t)(b * 256 + t) * 32000;
  __shared__ int sid;
  if (threadIdx.x == 0) sid = 0;
  __syncthreads();
  for (int base = threadIdx.x * 4; base < 32000; base += 1024) {
    const float4 v = *reinterpret_cast<const float4*>(row + base);
    if (v.x != 0.f) sid = base;
    if (v.y != 0.f) sid = base + 1;
    if (v.z != 0.f) sid = base + 2;
    if (v.w != 0.f) sid = base + 3;
  }
  __syncthreads();
  xb[(size_t)m * 256 + threadIdx.x] = f2bf(emb[(size_t)sid * 256 + threadIdx.x]);
}

// ---------------- Phase 1b: cast W_ih (f|b) to bf16, concatenated ----------
__global__ __launch_bounds__(256) void k_cast(const float* __restrict__ Wf,
                                              const float* __restrict__ Wb,
                                              unsigned short* __restrict__ Wc) {
  const int e = (blockIdx.x * 256 + threadIdx.x) * 4;   // 524288 elems total
  const float* src = (e < 1024 * 256) ? (Wf + e) : (Wb + (e - 1024 * 256));
  const float4 v = *reinterpret_cast<const float4*>(src);
  ushort4 o;
  o.x = f2bf(v.x); o.y = f2bf(v.y); o.z = f2bf(v.z); o.w = f2bf(v.w);
  *reinterpret_cast<ushort4*>(Wc + e) = o;
}

// ---------------- Phase 2: G = Xb @ Wcat^T + bias (bf16 MFMA) --------------
// grid 2048 = 64 m-tiles x 32 n-tiles, 256 thr. Wave wv: rows m0+wv*16..+16.
__global__ __launch_bounds__(256) void k_gemm(const unsigned short* __restrict__ Xb,
                                              const unsigned short* __restrict__ Wc,
                                              const float* __restrict__ bf,
                                              const float* __restrict__ bb,
                                              float* __restrict__ Gm) {
  const int tid = threadIdx.x;
  const int wv = tid >> 6, l = tid & 63, lr = l & 15, kg = l >> 4;
  const int m0 = (blockIdx.x >> 5) * 64;
  const int n0 = (blockIdx.x & 31) * 64;
  const int mrow = m0 + wv * 16 + lr;
  short8 afrag[8];
#pragma unroll
  for (int ks = 0; ks < 8; ++ks)
    afrag[ks] = *reinterpret_cast<const short8*>(Xb + (size_t)mrow * 256 + ks * 32 + kg * 8);
#pragma unroll
  for (int nt = 0; nt < 4; ++nt) {
    const int n = n0 + nt * 16 + lr;
    short8 bfrag[8];
#pragma unroll
    for (int ks = 0; ks < 8; ++ks)
      bfrag[ks] = *reinterpret_cast<const short8*>(Wc + (size_t)n * 256 + ks * 32 + kg * 8);
    f32x4 acc = {0.f, 0.f, 0.f, 0.f};
#pragma unroll
    for (int ks = 0; ks < 8; ++ks)
      acc = __builtin_amdgcn_mfma_f32_16x16x32_bf16(afrag[ks], bfrag[ks], acc, 0, 0, 0);
    const float bias = (n < 1024) ? bf[n] : bb[n - 1024];
#pragma unroll
    for (int r = 0; r < 4; ++r)
      Gm[(size_t)(m0 + wv * 16 + kg * 4 + r) * 2048 + n] = acc[r] + bias;
  }
}

// ---------------- Phase 3: bidirectional LSTM scan (MFMA, tagged exchange) --
// Grid: 8 WGs = 2 dirs x 4 WGs x 256 thr. WG (d,widx) owns j in [widx*64,+64);
// wave wv owns j in [j0+wv*16,+16) x all 4 gates. W_hh resident in VGPRs.
// Exchange protocol: h words are u32 (tag<<16)|bf16(h), tag = h-state index.
// Producers: 4 relaxed agent u32 stores (straight to L3 coherence point) —
// NO vmcnt drain / syncthreads / flags: each word self-validates. Consumers:
// per-wave independent spin reloading their A-fragment words until all 64
// carry tag==s. Parity double-buffer; safe because a WG reaches step s+1 only
// after ALL waves consumed h(s) (every wave reads the full h matrix).
// Critical path/step = one store-visibility + one poll-detect + 32 MFMA.
__global__ __launch_bounds__(256, 1) void k_scan(const float* __restrict__ Whf,
                                                 const float* __restrict__ Whb,
                                                 const int* __restrict__ lengths,
                                                 const float* __restrict__ Gm,
                                                 unsigned* hx,
                                                 float* __restrict__ out) {
  const int wg = blockIdx.x;
  const int d = wg >> 2;
  const int widx = wg & 3;
  const int j0 = widx * 64;
  const float* Wh = d ? Whb : Whf;
  const int tid = threadIdx.x;
  const int wv = tid >> 6;
  const int l = tid & 63;
  const int lr = l & 15;            // fragment row: b (A/C-row) or n (B-row)
  const int kg = l >> 4;            // k-group (8 contiguous k)
  const int j = j0 + wv * 16 + lr;

  // resident W_hh B-fragments: wfrag[g][ks] = W[g*256+j][ks*32 + kg*8 .. +8]
  short8 wfrag[4][8];
#pragma unroll
  for (int g = 0; g < 4; ++g) {
#pragma unroll
    for (int ks = 0; ks < 8; ++ks) {
      const float* wp = Wh + (size_t)(g * 256 + j) * 256 + ks * 32 + kg * 8;
      const float4 w0 = *reinterpret_cast<const float4*>(wp);
      const float4 w1 = *reinterpret_cast<const float4*>(wp + 4);
      short8 wv8;
      wv8[0] = (short)f2bf(w0.x); wv8[1] = (short)f2bf(w0.y);
      wv8[2] = (short)f2bf(w0.z); wv8[3] = (short)f2bf(w0.w);
      wv8[4] = (short)f2bf(w1.x); wv8[5] = (short)f2bf(w1.y);
      wv8[6] = (short)f2bf(w1.z); wv8[7] = (short)f2bf(w1.w);
      wfrag[g][ks] = wv8;
    }
  }

  int len4[4];
#pragma unroll
  for (int r = 0; r < 4; ++r) len4[r] = lengths[kg * 4 + r];

  float c_st[4] = {0.f, 0.f, 0.f, 0.f}, h_st[4] = {0.f, 0.f, 0.f, 0.f};

  unsigned* hxd = hx + d * 2 * 4096;     // [2 parity][16][256] tagged u32

  for (int s = 0; s < 256; ++s) {
    const int t = d ? (255 - s) : s;
    // G preactivations as MFMA C-in (plain cached loads; complete during poll)
    f32x4 acc[4];
    {
      const float* gp = Gm + (size_t)(t * 16 + kg * 4) * 2048 + d * 1024 + j;
#pragma unroll
      for (int g = 0; g < 4; ++g) {
#pragma unroll
        for (int r = 0; r < 4; ++r)
          acc[g][r] = gp[(size_t)r * 2048 + g * 256];
      }
    }
    // poll + gather h(s) A-fragments: lane (lr=b, kg), words k=ks*32+kg*8..+8
    short8 afrag[8];
    {
      const unsigned long long* hq =
          reinterpret_cast<const unsigned long long*>(hxd + (s & 1) * 4096);
      const unsigned long long expv =
          ((unsigned long long)s << 16) | ((unsigned long long)s << 48);
      const int base0 = lr * 128 + kg * 4;   // u64 units
      unsigned long long bad;
      do {
        bad = 0;
#pragma unroll
        for (int ks = 0; ks < 8; ++ks) {
          const unsigned long long* p = hq + base0 + ks * 16;
          const unsigned long long q0 = __hip_atomic_load(p + 0, __ATOMIC_RELAXED, __HIP_MEMORY_SCOPE_AGENT);
          const unsigned long long q1 = __hip_atomic_load(p + 1, __ATOMIC_RELAXED, __HIP_MEMORY_SCOPE_AGENT);
          const unsigned long long q2 = __hip_atomic_load(p + 2, __ATOMIC_RELAXED, __HIP_MEMORY_SCOPE_AGENT);
          const unsigned long long q3 = __hip_atomic_load(p + 3, __ATOMIC_RELAXED, __HIP_MEMORY_SCOPE_AGENT);
          bad |= (q0 ^ expv) & 0xFFFF0000FFFF0000ULL;
          bad |= (q1 ^ expv) & 0xFFFF0000FFFF0000ULL;
          bad |= (q2 ^ expv) & 0xFFFF0000FFFF0000ULL;
          bad |= (q3 ^ expv) & 0xFFFF0000FFFF0000ULL;
          uint4v u;
          u.x = pack_lo16(q0); u.y = pack_lo16(q1);
          u.z = pack_lo16(q2); u.w = pack_lo16(q3);
          afrag[ks] = __builtin_bit_cast(short8, u);
        }
      } while (__any(bad != 0ULL));
    }
    // recurrent GEMM: acc[g] += h_prev x W_hh[g]^T
#pragma unroll
    for (int ks = 0; ks < 8; ++ks) {
#pragma unroll
      for (int g = 0; g < 4; ++g)
        acc[g] = __builtin_amdgcn_mfma_f32_16x16x32_bf16(afrag[ks], wfrag[g][ks], acc[g], 0, 0, 0);
    }
    // activations + state update; lane owns (j, b = kg*4 + r)
    float hout[4];
#pragma unroll
    for (int r = 0; r < 4; ++r) {
      const float ig = sigm_f(acc[0][r]);
      const float fg = sigm_f(acc[1][r]);
      const float gt = tanh_f(acc[2][r]);
      const float og = sigm_f(acc[3][r]);
      const float cn = fmaf(fg, c_st[r], ig * gt);
      const float hn = og * tanh_f(cn);
      const bool msk = t < len4[r];
      c_st[r] = msk ? cn : c_st[r];
      h_st[r] = msk ? hn : h_st[r];
      hout[r] = msk ? hn : 0.f;
    }
    // publish h(s+1): fire-and-forget tagged stores (coalesced per 16 lanes)
    if (s < 255) {
      unsigned* dst = hxd + ((s + 1) & 1) * 4096;
      const unsigned tagv = (unsigned)(s + 1) << 16;
#pragma unroll
      for (int r = 0; r < 4; ++r)
        __hip_atomic_store(dst + (kg * 4 + r) * 256 + j, tagv | (unsigned)f2bf(h_st[r]),
                           __ATOMIC_RELAXED, __HIP_MEMORY_SCOPE_AGENT);
    }
    // output store (off the critical path)
#pragma unroll
    for (int r = 0; r < 4; ++r)
      out[((size_t)(kg * 4 + r) * 256 + t) * 512 + d * 256 + j] = hout[r];
  }
}

extern "C" void kernel_launch(void* const* d_in, const int* in_sizes, int n_in,
                              void* d_out, int out_size, void* d_ws, size_t ws_size,
                              hipStream_t stream) {
  const float* seq = (const float*)d_in[0];
  const float* emb = (const float*)d_in[1];
  const float* Wif = (const float*)d_in[2];
  const float* Whf = (const float*)d_in[3];
  const float* bf  = (const float*)d_in[4];
  const float* Wib = (const float*)d_in[5];
  const float* Whb = (const float*)d_in[6];
  const float* bbv = (const float*)d_in[7];
  const int* lengths = (const int*)d_in[8];
  float* out = (float*)d_out;
  char* ws = (char*)d_ws;
  unsigned short* xb = (unsigned short*)(ws + X_OFF);
  unsigned short* wc = (unsigned short*)(ws + W_OFF);
  float* Gm = (float*)(ws + G_OFF);
  unsigned* hx = (unsigned*)(ws + HX_OFF);

  // zero the tagged h-exchange buffers every launch (ws is re-poisoned)
  hipMemsetAsync(d_ws, 0, MS_BYTES, stream);
  k_embed<<<dim3(4096), dim3(256), 0, stream>>>(seq, emb, xb);
  k_cast<<<dim3(512), dim3(256), 0, stream>>>(Wif, Wib, wc);
  k_gemm<<<dim3(2048), dim3(256), 0, stream>>>(xb, wc, bf, bbv, Gm);
  k_scan<<<dim3(8), dim3(256), 0, stream>>>(Whf, Whb, lengths, Gm, hx, out);
}

// Round 8
// 1481.555 us; speedup vs baseline: 2.0845x; 2.0845x over previous
//
#include <hip/hip_runtime.h>
#include <cstddef>
#include <cstdint>

// Problem dims: B=16, L=256, V=32000, E=256, H=256
// ws layout (bytes):
//   [0, 65536)       h exchange: [2 dir][2 parity][16 b][256 j] u32 = (tag<<16)|bf16(h)
//   [65536, 81920)   ids: 4096 i32 (one-hot index per (b,t) row)
//   [131072, +2MB)   Xb bf16 [4096 m][256 e], m = t*16 + b
//   [+2MB, +3MB)     Wcat bf16 [2048 n][256 k]
//   [+3MB, +36.5MB)  Gm f32 [4096 m][2048 n], n = dir*1024 + gate*256 + j
#define HX_OFF   0
#define IDS_OFF  65536
#define MS_BYTES 65536
#define X_OFF    131072
#define W_OFF    (X_OFF + 4096 * 256 * 2)
#define G_OFF    (W_OFF + 2048 * 256 * 2)

typedef __attribute__((ext_vector_type(8))) short short8;
typedef __attribute__((ext_vector_type(4))) float f32x4;
typedef __attribute__((ext_vector_type(4))) unsigned uint4v;

__device__ __forceinline__ unsigned short f2bf(float f) {
  unsigned u = __builtin_bit_cast(unsigned, f);
  u = (u + 0x7fffu + ((u >> 16) & 1u)) >> 16;   // round-to-nearest-even
  return (unsigned short)u;
}
__device__ __forceinline__ float sigm_f(float x) {
  return __builtin_amdgcn_rcpf(1.f + __expf(-x));
}
__device__ __forceinline__ float tanh_f(float x) {
  return 1.f - 2.f * __builtin_amdgcn_rcpf(1.f + __expf(2.f * x));
}
// low16 of both u32 halves of q, packed into one u32 (2 bf16)
__device__ __forceinline__ unsigned pack_lo16(unsigned long long q) {
  return ((unsigned)q & 0xFFFFu) | ((unsigned)(q >> 32) << 16);
}

// ---------------- Phase 1a: flat one-hot scan -> ids -----------------------
// Pure-BW grid-stride pass over 524 MB (no per-(b,t) block structure).
__global__ __launch_bounds__(256) void k_find(const float* __restrict__ seq,
                                              int* __restrict__ ids) {
  const int stride = gridDim.x * blockDim.x;
  const f32x4* s4 = reinterpret_cast<const f32x4*>(seq);
  for (int p = blockIdx.x * 256 + threadIdx.x; p < 32768000; p += stride) {
    const f32x4 v = __builtin_nontemporal_load(s4 + p);
    if (v.x != 0.f || v.y != 0.f || v.z != 0.f || v.w != 0.f) {
      const int flat = p * 4 + (v.x != 0.f ? 0 : v.y != 0.f ? 1 : v.z != 0.f ? 2 : 3);
      const int row = flat / 32000;          // row = b*256 + t
      ids[row] = flat - row * 32000;
    }
  }
}

// ---------------- Phase 1b: gather embedding rows (bf16 out) ---------------
__global__ __launch_bounds__(256) void k_gather(const float* __restrict__ emb,
                                                const int* __restrict__ ids,
                                                unsigned short* __restrict__ xb) {
  const int m = blockIdx.x;          // m = t*16 + b
  const int t = m >> 4, b = m & 15;
  const int id = ids[b * 256 + t];
  xb[(size_t)m * 256 + threadIdx.x] = f2bf(emb[(size_t)id * 256 + threadIdx.x]);
}

// ---------------- Phase 1c: cast W_ih (f|b) to bf16, concatenated ----------
__global__ __launch_bounds__(256) void k_cast(const float* __restrict__ Wf,
                                              const float* __restrict__ Wb,
                                              unsigned short* __restrict__ Wc) {
  const int e = (blockIdx.x * 256 + threadIdx.x) * 4;
  const float* src = (e < 1024 * 256) ? (Wf + e) : (Wb + (e - 1024 * 256));
  const float4 v = *reinterpret_cast<const float4*>(src);
  ushort4 o;
  o.x = f2bf(v.x); o.y = f2bf(v.y); o.z = f2bf(v.z); o.w = f2bf(v.w);
  *reinterpret_cast<ushort4*>(Wc + e) = o;
}

// ---------------- Phase 2: G = Xb @ Wcat^T + bias (bf16 MFMA) --------------
__global__ __launch_bounds__(256) void k_gemm(const unsigned short* __restrict__ Xb,
                                              const unsigned short* __restrict__ Wc,
                                              const float* __restrict__ bf,
                                              const float* __restrict__ bb,
                                              float* __restrict__ Gm) {
  const int tid = threadIdx.x;
  const int wv = tid >> 6, l = tid & 63, lr = l & 15, kg = l >> 4;
  const int m0 = (blockIdx.x >> 5) * 64;
  const int n0 = (blockIdx.x & 31) * 64;
  const int mrow = m0 + wv * 16 + lr;
  short8 afrag[8];
#pragma unroll
  for (int ks = 0; ks < 8; ++ks)
    afrag[ks] = *reinterpret_cast<const short8*>(Xb + (size_t)mrow * 256 + ks * 32 + kg * 8);
#pragma unroll
  for (int nt = 0; nt < 4; ++nt) {
    const int n = n0 + nt * 16 + lr;
    short8 bfrag[8];
#pragma unroll
    for (int ks = 0; ks < 8; ++ks)
      bfrag[ks] = *reinterpret_cast<const short8*>(Wc + (size_t)n * 256 + ks * 32 + kg * 8);
    f32x4 acc = {0.f, 0.f, 0.f, 0.f};
#pragma unroll
    for (int ks = 0; ks < 8; ++ks)
      acc = __builtin_amdgcn_mfma_f32_16x16x32_bf16(afrag[ks], bfrag[ks], acc, 0, 0, 0);
    const float bias = (n < 1024) ? bf[n] : bb[n - 1024];
#pragma unroll
    for (int r = 0; r < 4; ++r)
      Gm[(size_t)(m0 + wv * 16 + kg * 4 + r) * 2048 + n] = acc[r] + bias;
  }
}

// ---------------- Phase 3: bidirectional LSTM scan (MFMA) ------------------
// Grid: 8 WGs = 2 dirs x 4 WGs x 256 thr. WG (d,widx) owns j in [widx*64,+64);
// wave wv owns j in [j0+wv*16,+16) x all 4 gates. W_hh resident in VGPRs.
//
// Exchange protocol (agent scope = L3 coherence point, proven r2-r5):
// h words are u32 (tag<<16)|bf16, tag = h-state index; parity double-buffer.
// Producers: 4 relaxed agent stores, fire-and-forget (words self-validate -
// no drain/flags/fences). Consumers: ONE poller wave per WG (wave 0) polls
// the full 16KB h matrix until all its words carry tag==s, then rebroadcasts
// via swizzled LDS; waves 1-3 park at __syncthreads. This keeps round-5's
// single-visibility-hop chain but cuts agent-poll traffic 4x (8 pollers, not
// 32) + s_sleep backoff -> no L3 congestion collapse (round-5 failure mode).
// Safety: wave0 overwrites h_lds for s+1 only after poll(s+1) succeeds, which
// requires every wave's tag-(s+1) stores, which value-depend on their LDS
// reads of h(s) -> no WAR race. Parity reuse safe as in round 5.
__global__ __launch_bounds__(256, 1) void k_scan(const float* __restrict__ Whf,
                                                 const float* __restrict__ Whb,
                                                 const int* __restrict__ lengths,
                                                 const float* __restrict__ Gm,
                                                 unsigned* hx,
                                                 float* __restrict__ out) {
  const int wg = blockIdx.x;
  const int d = wg >> 2;
  const int widx = wg & 3;
  const int j0 = widx * 64;
  const float* Wh = d ? Whb : Whf;
  const int tid = threadIdx.x;
  const int wv = tid >> 6;
  const int l = tid & 63;
  const int lr = l & 15;            // fragment row: b (A/C) or n (B)
  const int kg = l >> 4;            // k-group (8 contiguous k)
  const int j = j0 + wv * 16 + lr;

  // resident W_hh B-fragments: wfrag[g][ks] = W[g*256+j][ks*32 + kg*8 .. +8]
  short8 wfrag[4][8];
#pragma unroll
  for (int g = 0; g < 4; ++g) {
#pragma unroll
    for (int ks = 0; ks < 8; ++ks) {
      const float* wp = Wh + (size_t)(g * 256 + j) * 256 + ks * 32 + kg * 8;
      const float4 w0 = *reinterpret_cast<const float4*>(wp);
      const float4 w1 = *reinterpret_cast<const float4*>(wp + 4);
      short8 w8;
      w8[0] = (short)f2bf(w0.x); w8[1] = (short)f2bf(w0.y);
      w8[2] = (short)f2bf(w0.z); w8[3] = (short)f2bf(w0.w);
      w8[4] = (short)f2bf(w1.x); w8[5] = (short)f2bf(w1.y);
      w8[6] = (short)f2bf(w1.z); w8[7] = (short)f2bf(w1.w);
      wfrag[g][ks] = w8;
    }
  }

  int len4[4];
#pragma unroll
  for (int r = 0; r < 4; ++r) len4[r] = lengths[kg * 4 + r];

  float c_st[4] = {0.f, 0.f, 0.f, 0.f}, h_st[4] = {0.f, 0.f, 0.f, 0.f};
  unsigned* hxq = hx + d * 8192;    // [2 parity][16 b][256 j] tagged u32

  __shared__ unsigned short h_lds[16 * 256];   // swizzled bf16 h(s), 8KB

  for (int s = 0; s < 256; ++s) {
    const int t = d ? (255 - s) : s;
    // G preactivations straight into the MFMA C-in (complete under the poll)
    f32x4 acc[4];
    {
      const float* gp = Gm + (size_t)(t * 16 + kg * 4) * 2048 + d * 1024 + j;
#pragma unroll
      for (int g = 0; g < 4; ++g)
#pragma unroll
        for (int r = 0; r < 4; ++r)
          acc[g][r] = gp[(size_t)r * 2048 + g * 256];
    }
    short8 afrag[8];
    if (wv == 0) {
      // --- poller: self-validating tagged poll over the full h(s) ---
      const unsigned long long* hq =
          reinterpret_cast<const unsigned long long*>(hxq + (s & 1) * 4096);
      const unsigned long long expv =
          ((unsigned long long)s << 16) | ((unsigned long long)s << 48);
      const int base0 = lr * 128 + kg * 4;   // u64 units
      unsigned long long bad;
      do {
        bad = 0;
#pragma unroll
        for (int ks = 0; ks < 8; ++ks) {
          const unsigned long long* p = hq + base0 + ks * 16;
          const unsigned long long q0 = __hip_atomic_load(p + 0, __ATOMIC_RELAXED, __HIP_MEMORY_SCOPE_AGENT);
          const unsigned long long q1 = __hip_atomic_load(p + 1, __ATOMIC_RELAXED, __HIP_MEMORY_SCOPE_AGENT);
          const unsigned long long q2 = __hip_atomic_load(p + 2, __ATOMIC_RELAXED, __HIP_MEMORY_SCOPE_AGENT);
          const unsigned long long q3 = __hip_atomic_load(p + 3, __ATOMIC_RELAXED, __HIP_MEMORY_SCOPE_AGENT);
          bad |= (q0 ^ expv) & 0xFFFF0000FFFF0000ULL;
          bad |= (q1 ^ expv) & 0xFFFF0000FFFF0000ULL;
          bad |= (q2 ^ expv) & 0xFFFF0000FFFF0000ULL;
          bad |= (q3 ^ expv) & 0xFFFF0000FFFF0000ULL;
          uint4v u;
          u.x = pack_lo16(q0); u.y = pack_lo16(q1);
          u.z = pack_lo16(q2); u.w = pack_lo16(q3);
          afrag[ks] = __builtin_bit_cast(short8, u);
        }
        if (!__any(bad != 0ULL)) break;
        __builtin_amdgcn_s_sleep(1);          // backoff: keep L3 unloaded
      } while (true);
      // broadcast to LDS, XOR-swizzled 16B slots (G4: avoid 16-way conflict)
#pragma unroll
      for (int ks = 0; ks < 8; ++ks) {
        const int boff = lr * 512 + ((ks * 64 + kg * 16) ^ ((lr & 7) << 4));
        *reinterpret_cast<short8*>(reinterpret_cast<char*>(h_lds) + boff) = afrag[ks];
      }
    }
    __syncthreads();
    if (wv != 0) {
#pragma unroll
      for (int ks = 0; ks < 8; ++ks) {
        const int boff = lr * 512 + ((ks * 64 + kg * 16) ^ ((lr & 7) << 4));
        afrag[ks] = *reinterpret_cast<const short8*>(reinterpret_cast<const char*>(h_lds) + boff);
      }
    }

    // recurrent GEMM: acc[g] = G + h_prev x W_hh[g]^T
#pragma unroll
    for (int ks = 0; ks < 8; ++ks)
#pragma unroll
      for (int g = 0; g < 4; ++g)
        acc[g] = __builtin_amdgcn_mfma_f32_16x16x32_bf16(afrag[ks], wfrag[g][ks], acc[g], 0, 0, 0);

    // activations + state; lane owns (j, b = kg*4 + r)
    float hout[4];
#pragma unroll
    for (int r = 0; r < 4; ++r) {
      const float ig = sigm_f(acc[0][r]);
      const float fg = sigm_f(acc[1][r]);
      const float gt = tanh_f(acc[2][r]);
      const float og = sigm_f(acc[3][r]);
      const float cn = fmaf(fg, c_st[r], ig * gt);
      const float hn = og * tanh_f(cn);
      const bool msk = t < len4[r];
      c_st[r] = msk ? cn : c_st[r];
      h_st[r] = msk ? hn : h_st[r];
      hout[r] = msk ? hn : 0.f;
    }
    // publish h(s+1): fire-and-forget tagged agent stores (self-validating)
    if (s < 255) {
      unsigned* dst = hxq + ((s + 1) & 1) * 4096;
      const unsigned tagv = (unsigned)(s + 1) << 16;
#pragma unroll
      for (int r = 0; r < 4; ++r)
        __hip_atomic_store(dst + (kg * 4 + r) * 256 + j, tagv | (unsigned)f2bf(h_st[r]),
                           __ATOMIC_RELAXED, __HIP_MEMORY_SCOPE_AGENT);
    }
    // output store (nontemporal, off the critical path)
#pragma unroll
    for (int r = 0; r < 4; ++r)
      __builtin_nontemporal_store(hout[r],
          out + ((size_t)(kg * 4 + r) * 256 + t) * 512 + d * 256 + j);
  }
}

extern "C" void kernel_launch(void* const* d_in, const int* in_sizes, int n_in,
                              void* d_out, int out_size, void* d_ws, size_t ws_size,
                              hipStream_t stream) {
  const float* seq = (const float*)d_in[0];
  const float* emb = (const float*)d_in[1];
  const float* Wif = (const float*)d_in[2];
  const float* Whf = (const float*)d_in[3];
  const float* bf  = (const float*)d_in[4];
  const float* Wib = (const float*)d_in[5];
  const float* Whb = (const float*)d_in[6];
  const float* bbv = (const float*)d_in[7];
  const int* lengths = (const int*)d_in[8];
  float* out = (float*)d_out;
  char* ws = (char*)d_ws;
  int* ids = (int*)(ws + IDS_OFF);
  unsigned short* xb = (unsigned short*)(ws + X_OFF);
  unsigned short* wc = (unsigned short*)(ws + W_OFF);
  float* Gm = (float*)(ws + G_OFF);
  unsigned* hx = (unsigned*)(ws + HX_OFF);

  // zero the tagged h-exchange buffers every launch (ws is re-poisoned)
  (void)hipMemsetAsync(d_ws, 0, MS_BYTES, stream);
  k_find<<<dim3(2048), dim3(256), 0, stream>>>(seq, ids);
  k_gather<<<dim3(4096), dim3(256), 0, stream>>>(emb, ids, xb);
  k_cast<<<dim3(512), dim3(256), 0, stream>>>(Wif, Wib, wc);
  k_gemm<<<dim3(2048), dim3(256), 0, stream>>>(xb, wc, bf, bbv, Gm);
  k_scan<<<dim3(8), dim3(256), 0, stream>>>(Whf, Whb, lengths, Gm, hx, out);
}